// Round 16
// baseline (193.171 us; speedup 1.0000x reference)
//
#include <hip/hip_runtime.h>

#define NN 100000
#define NE 1600000
#define INF 128
#define HID 64
#define LN_EPS 1e-5f

#define BINB 9
#define BINSZ 512
#define NBIN 196
#define FILLB 512
#define BCAP 9250   // fixed bin slot capacity (Poisson(8163) + 12 sigma)

typedef unsigned short u16;
typedef __attribute__((ext_vector_type(8))) short bf16x8;
typedef __attribute__((ext_vector_type(4))) float f32x4;

#define SAP 136   // padded LDS row stride (bf16 elems)

__device__ __forceinline__ u16 f2bf(float f) {
    unsigned u = __float_as_uint(f);
    return (u16)((u + 0x7FFFu + ((u >> 16) & 1u)) >> 16);
}
__device__ __forceinline__ unsigned pack2bf(float a, float b) {
    unsigned ua = __float_as_uint(a), ub = __float_as_uint(b);
    ua = (ua + 0x7FFFu + ((ua >> 16) & 1u)) >> 16;
    ub = (ub + 0x7FFFu + ((ub >> 16) & 1u)) >> 16;
    return ua | (ub << 16);
}
__device__ __forceinline__ unsigned pkmax(unsigned a, unsigned b) {
    unsigned r;
    asm("v_pk_max_u16 %0, %1, %2" : "=v"(r) : "v"(a), "v"(b));
    return r;
}
__device__ __forceinline__ uint4 pkmax4(uint4 a, uint4 b) {
    return make_uint4(pkmax(a.x, b.x), pkmax(a.y, b.y), pkmax(a.z, b.z), pkmax(a.w, b.w));
}

// ---------------- CSR build: slotted binned counting sort ----------------

__global__ __launch_bounds__(256) void k_zero(int* __restrict__ bincur) {
    int i = threadIdx.x;
    if (i < NBIN) bincur[i] = 0;
}

__global__ __launch_bounds__(256) void k_binfill(const int* __restrict__ src, const int* __restrict__ dst,
                                                 int* __restrict__ bincur, unsigned* __restrict__ binpair) {
    __shared__ int cnt[NBIN];
    __shared__ int base[NBIN];
    __shared__ int cur[NBIN];
    int tid = threadIdx.x;
    const int chunk = (NE + FILLB - 1) / FILLB;
    int s = blockIdx.x * chunk;
    int t = min(s + chunk, NE);

    for (int i = tid; i < NBIN; i += 256) cnt[i] = 0;
    __syncthreads();
    for (int e = s + tid; e < t; e += 256) atomicAdd(&cnt[dst[e] >> BINB], 1);
    __syncthreads();
    for (int i = tid; i < NBIN; i += 256) {
        int c = cnt[i];
        base[i] = c ? atomicAdd(&bincur[i], c) : 0;
        cur[i] = 0;
    }
    __syncthreads();
    for (int e = s + tid; e < t; e += 256) {
        int d = dst[e];
        int b = d >> BINB;
        int pos = base[b] + atomicAdd(&cur[b], 1);
        binpair[(size_t)b * BCAP + pos] = ((unsigned)src[e] << BINB) | (unsigned)(d & (BINSZ - 1));
    }
}

__global__ __launch_bounds__(256) void k_binsort(const unsigned* __restrict__ binpair,
                                                 const int* __restrict__ bincur,
                                                 int* __restrict__ rowptr, int* __restrict__ deg,
                                                 int* __restrict__ eidx) {
    __shared__ int cnt[BINSZ];
    __shared__ int ofs[BINSZ];
    __shared__ int cur[BINSZ];
    int tid = threadIdx.x, lane = tid & 63, wid = tid >> 6;
    int b = blockIdx.x;
    int s = b * BCAP;
    int t = s + bincur[b];

    cnt[tid] = 0; cnt[tid + 256] = 0;
    __syncthreads();
    for (int e = s + tid; e < t; e += 256) atomicAdd(&cnt[binpair[e] & (BINSZ - 1)], 1);
    __syncthreads();

    int a0 = cnt[2 * tid], a1 = cnt[2 * tid + 1];
    int ps = a0 + a1;
    int v = ps;
    #pragma unroll
    for (int d = 1; d < 64; d <<= 1) { int y = __shfl_up(v, d); if (lane >= d) v += y; }
    __shared__ int wsum[4];
    if (lane == 63) wsum[wid] = v;
    __syncthreads();
    int add = 0;
    for (int w = 0; w < wid; ++w) add += wsum[w];
    int excl = v + add - ps;
    ofs[2 * tid] = excl; ofs[2 * tid + 1] = excl + a0;
    cur[2 * tid] = excl; cur[2 * tid + 1] = excl + a0;
    __syncthreads();

    int nodeBase = b << BINB;
    #pragma unroll
    for (int j = 0; j < 2; ++j) {
        int i = tid + j * 256;
        int n = nodeBase + i;
        if (n < NN) { rowptr[n] = s + ofs[i]; deg[n] = cnt[i]; }
    }

    for (int e = s + tid; e < t; e += 256) {
        unsigned p = binpair[e];
        int l = p & (BINSZ - 1);
        int pos = s + atomicAdd(&cur[l], 1);
        eidx[pos] = (int)(p >> BINB);
    }
}

// ---------------- W convert: f32 [128][64] -> bf16 transposed [64][128] ----------------

__global__ __launch_bounds__(256) void k_wconv(const float* __restrict__ Ws, u16* __restrict__ wtb) {
    int L = blockIdx.x, tid = threadIdx.x;
    int c = tid & 63, k0 = (tid >> 6) * 32;
    const float* W = Ws + (size_t)L * INF * HID;
    alignas(16) u16 tmp[32];
    #pragma unroll
    for (int k = 0; k < 32; ++k) tmp[k] = f2bf(W[(size_t)(k0 + k) * HID + c]);
    u16* dstp = wtb + (size_t)L * HID * INF + (size_t)c * INF + k0;
    #pragma unroll
    for (int j = 0; j < 4; ++j)
        *(uint4*)(dstp + j * 8) = *(uint4*)&tmp[j * 8];
}

// ---------------- MFMA Linear + LayerNorm + ReLU ----------------

template<int KIND>
__global__ __launch_bounds__(256) void k_mlp(
    const float* __restrict__ fin,
    u16* xbf,
    const u16* __restrict__ wtb,
    const float* __restrict__ bias, const float* __restrict__ gam, const float* __restrict__ bet,
    float* __restrict__ fout)
{
    __shared__ u16 sA[64 * SAP];
    __shared__ u16 sB[64 * SAP];

    const int tid = threadIdx.x, lane = tid & 63;
    const int w = __builtin_amdgcn_readfirstlane(tid >> 6);
    const int node0 = blockIdx.x * 64;

    if (KIND == 0) {
        #pragma unroll
        for (int j = 0; j < 8; ++j) {
            int f4 = tid + j * 256;
            int nl = f4 >> 5, k4 = f4 & 31;
            int n = node0 + nl; if (n >= NN) n = NN - 1;
            float4 v = *(const float4*)(fin + (size_t)n * INF + k4 * 4);
            *(uint2*)&sA[nl * SAP + k4 * 4] = make_uint2(pack2bf(v.x, v.y), pack2bf(v.z, v.w));
        }
    } else {
        #pragma unroll
        for (int j = 0; j < 4; ++j) {
            int ch = tid + j * 256;
            int nl = ch >> 4, c8 = ch & 15;
            int n = node0 + nl; if (n >= NN) n = NN - 1;
            *(uint4*)&sA[nl * SAP + c8 * 8] = *(const uint4*)(xbf + (size_t)n * INF + c8 * 8);
        }
    }
    #pragma unroll
    for (int j = 0; j < 4; ++j) {
        int ch = tid + j * 256;
        int r = ch >> 4, k8 = ch & 15;
        *(uint4*)&sB[r * SAP + k8 * 8] = *(const uint4*)(wtb + (size_t)r * INF + k8 * 8);
    }

    const int cl = lane & 15;
    float bC[4], gC[4], tC[4];
    #pragma unroll
    for (int nt = 0; nt < 4; ++nt) {
        int c = nt * 16 + cl;
        bC[nt] = bias[c]; gC[nt] = gam[c]; tC[nt] = bet[c];
    }

    __syncthreads();

    f32x4 acc[4] = {(f32x4)0.f, (f32x4)0.f, (f32x4)0.f, (f32x4)0.f};
    const int kg = (lane >> 4) * 8;
    #pragma unroll
    for (int kk = 0; kk < 4; ++kk) {
        bf16x8 a = *(const bf16x8*)&sA[(w * 16 + cl) * SAP + kk * 32 + kg];
        #pragma unroll
        for (int nt = 0; nt < 4; ++nt) {
            bf16x8 b = *(const bf16x8*)&sB[(nt * 16 + cl) * SAP + kk * 32 + kg];
            acc[nt] = __builtin_amdgcn_mfma_f32_16x16x32_bf16(a, b, acc[nt], 0, 0, 0);
        }
    }

    #pragma unroll
    for (int nt = 0; nt < 4; ++nt)
        #pragma unroll
        for (int r = 0; r < 4; ++r) acc[nt][r] += bC[nt];

    float mu[4], rs[4];
    #pragma unroll
    for (int r = 0; r < 4; ++r) {
        float s = acc[0][r] + acc[1][r] + acc[2][r] + acc[3][r];
        float q = acc[0][r]*acc[0][r] + acc[1][r]*acc[1][r] + acc[2][r]*acc[2][r] + acc[3][r]*acc[3][r];
        #pragma unroll
        for (int m = 1; m < 16; m <<= 1) { s += __shfl_xor(s, m); q += __shfl_xor(q, m); }
        mu[r] = s * 0.015625f;
        float var = fmaxf(q * 0.015625f - mu[r] * mu[r], 0.f);
        rs[r] = rsqrtf(var + LN_EPS);
    }

    #pragma unroll
    for (int nt = 0; nt < 4; ++nt) {
        int c = nt * 16 + cl;
        #pragma unroll
        for (int r = 0; r < 4; ++r) {
            int row = w * 16 + (lane >> 4) * 4 + r;
            float o = fmaxf((acc[nt][r] - mu[r]) * rs[r] * gC[nt] + tC[nt], 0.f);
            sA[row * SAP + c] = f2bf(o);
            if (KIND == 2) {
                int n = node0 + row;
                if (n < NN) fout[(size_t)n * 128 + c] = o;
            }
        }
    }

    #pragma unroll
    for (int i = 0; i < 2; ++i) {
        int ch = lane + i * 64;
        int r16 = ch >> 3, c8 = ch & 7;
        int row = w * 16 + r16;
        int n = node0 + row;
        if (n < NN)
            *(uint4*)(xbf + (size_t)n * INF + c8 * 8) = *(const uint4*)&sA[row * SAP + c8 * 8];
    }
}

// ---------------- per-dst segment max over bf16 rows (paired-edge uint4) ----------------
// group(16 lanes) = 1 dst node, split 2x8: each 8-lane half = a different edge,
// lane = 8 features (uint4). Unroll 8 pairs => 16 edges (8 x 16B loads/lane) in
// flight per group. eidx via nontemporal loads (don't evict h pool from L2).

__global__ __launch_bounds__(256) void k_gather_bb(
    const u16* __restrict__ hb, const int* __restrict__ rowptr, const int* __restrict__ deg,
    const int* __restrict__ eidx, u16* __restrict__ aggb)
{
    int tid = threadIdx.x, lane = tid & 63, wid = tid >> 6;
    int nw0 = blockIdx.x * 16 + wid * 4;
    int g = lane >> 4, sub = (lane >> 3) & 1, fl = lane & 7;
    int n = nw0 + g;

    int rp = (lane < 4) ? rowptr[nw0 + lane] : 0;
    int dv = (lane < 4) ? deg[nw0 + lane] : 0;
    int start = __shfl(rp, g);
    int dg    = __shfl(dv, g);

    uint4 m = make_uint4(0, 0, 0, 0);
    if (dg == 0) {
        m = *(const uint4*)(hb + (size_t)n * 128 + fl * 8);
    } else {
        int endm1 = start + dg - 1;
        int iters = (dg + 1) >> 1;
        int e = start + sub;
        int it = 0;
        for (; it + 8 <= iters; it += 8, e += 16) {
            int ei[8];
            #pragma unroll
            for (int u = 0; u < 8; ++u)
                ei[u] = __builtin_nontemporal_load(eidx + min(e + u * 2, endm1));
            uint4 v0 = *(const uint4*)(hb + (size_t)ei[0] * 128 + fl * 8);
            uint4 v1 = *(const uint4*)(hb + (size_t)ei[1] * 128 + fl * 8);
            uint4 v2 = *(const uint4*)(hb + (size_t)ei[2] * 128 + fl * 8);
            uint4 v3 = *(const uint4*)(hb + (size_t)ei[3] * 128 + fl * 8);
            uint4 v4 = *(const uint4*)(hb + (size_t)ei[4] * 128 + fl * 8);
            uint4 v5 = *(const uint4*)(hb + (size_t)ei[5] * 128 + fl * 8);
            uint4 v6 = *(const uint4*)(hb + (size_t)ei[6] * 128 + fl * 8);
            uint4 v7 = *(const uint4*)(hb + (size_t)ei[7] * 128 + fl * 8);
            m = pkmax4(m, pkmax4(pkmax4(pkmax4(v0, v1), pkmax4(v2, v3)),
                                 pkmax4(pkmax4(v4, v5), pkmax4(v6, v7))));
        }
        for (; it + 4 <= iters; it += 4, e += 8) {
            int e0 = min(e, endm1),     e1 = min(e + 2, endm1);
            int e2 = min(e + 4, endm1), e3 = min(e + 6, endm1);
            int i0 = __builtin_nontemporal_load(eidx + e0);
            int i1 = __builtin_nontemporal_load(eidx + e1);
            int i2 = __builtin_nontemporal_load(eidx + e2);
            int i3 = __builtin_nontemporal_load(eidx + e3);
            uint4 v0 = *(const uint4*)(hb + (size_t)i0 * 128 + fl * 8);
            uint4 v1 = *(const uint4*)(hb + (size_t)i1 * 128 + fl * 8);
            uint4 v2 = *(const uint4*)(hb + (size_t)i2 * 128 + fl * 8);
            uint4 v3 = *(const uint4*)(hb + (size_t)i3 * 128 + fl * 8);
            m = pkmax4(m, pkmax4(pkmax4(v0, v1), pkmax4(v2, v3)));
        }
        for (; it < iters; ++it, e += 2) {
            int i0 = __builtin_nontemporal_load(eidx + min(e, endm1));
            uint4 v = *(const uint4*)(hb + (size_t)i0 * 128 + fl * 8);
            m = pkmax4(m, v);
        }
        m.x = pkmax(m.x, (unsigned)__shfl_xor((int)m.x, 8));
        m.y = pkmax(m.y, (unsigned)__shfl_xor((int)m.y, 8));
        m.z = pkmax(m.z, (unsigned)__shfl_xor((int)m.z, 8));
        m.w = pkmax(m.w, (unsigned)__shfl_xor((int)m.w, 8));
    }
    if (sub == 0)
        *(uint4*)(aggb + (size_t)n * 128 + fl * 8) = m;
}

__global__ __launch_bounds__(256) void k_gather_bf(
    const u16* __restrict__ hb, const int* __restrict__ rowptr, const int* __restrict__ deg,
    const int* __restrict__ eidx, float* __restrict__ out)
{
    int tid = threadIdx.x, lane = tid & 63, wid = tid >> 6;
    int nw0 = blockIdx.x * 16 + wid * 4;
    int g = lane >> 4, sub = (lane >> 3) & 1, fl = lane & 7;
    int n = nw0 + g;

    int rp = (lane < 4) ? rowptr[nw0 + lane] : 0;
    int dv = (lane < 4) ? deg[nw0 + lane] : 0;
    int start = __shfl(rp, g);
    int dg    = __shfl(dv, g);

    if (dg == 0) {   // exact f32 self feature
        if (sub == 0) {
            f32x4 a = *(const f32x4*)(out + (size_t)n * 128 + fl * 8);
            f32x4 b = *(const f32x4*)(out + (size_t)n * 128 + fl * 8 + 4);
            *(f32x4*)(out + (size_t)n * 128 + 64 + fl * 8) = a;
            *(f32x4*)(out + (size_t)n * 128 + 64 + fl * 8 + 4) = b;
        }
        return;
    }

    uint4 m = make_uint4(0, 0, 0, 0);
    int endm1 = start + dg - 1;
    int iters = (dg + 1) >> 1;
    int e = start + sub;
    int it = 0;
    for (; it + 8 <= iters; it += 8, e += 16) {
        int ei[8];
        #pragma unroll
        for (int u = 0; u < 8; ++u)
            ei[u] = __builtin_nontemporal_load(eidx + min(e + u * 2, endm1));
        uint4 v0 = *(const uint4*)(hb + (size_t)ei[0] * 128 + fl * 8);
        uint4 v1 = *(const uint4*)(hb + (size_t)ei[1] * 128 + fl * 8);
        uint4 v2 = *(const uint4*)(hb + (size_t)ei[2] * 128 + fl * 8);
        uint4 v3 = *(const uint4*)(hb + (size_t)ei[3] * 128 + fl * 8);
        uint4 v4 = *(const uint4*)(hb + (size_t)ei[4] * 128 + fl * 8);
        uint4 v5 = *(const uint4*)(hb + (size_t)ei[5] * 128 + fl * 8);
        uint4 v6 = *(const uint4*)(hb + (size_t)ei[6] * 128 + fl * 8);
        uint4 v7 = *(const uint4*)(hb + (size_t)ei[7] * 128 + fl * 8);
        m = pkmax4(m, pkmax4(pkmax4(pkmax4(v0, v1), pkmax4(v2, v3)),
                             pkmax4(pkmax4(v4, v5), pkmax4(v6, v7))));
    }
    for (; it + 4 <= iters; it += 4, e += 8) {
        int e0 = min(e, endm1),     e1 = min(e + 2, endm1);
        int e2 = min(e + 4, endm1), e3 = min(e + 6, endm1);
        int i0 = __builtin_nontemporal_load(eidx + e0);
        int i1 = __builtin_nontemporal_load(eidx + e1);
        int i2 = __builtin_nontemporal_load(eidx + e2);
        int i3 = __builtin_nontemporal_load(eidx + e3);
        uint4 v0 = *(const uint4*)(hb + (size_t)i0 * 128 + fl * 8);
        uint4 v1 = *(const uint4*)(hb + (size_t)i1 * 128 + fl * 8);
        uint4 v2 = *(const uint4*)(hb + (size_t)i2 * 128 + fl * 8);
        uint4 v3 = *(const uint4*)(hb + (size_t)i3 * 128 + fl * 8);
        m = pkmax4(m, pkmax4(pkmax4(v0, v1), pkmax4(v2, v3)));
    }
    for (; it < iters; ++it, e += 2) {
        int i0 = __builtin_nontemporal_load(eidx + min(e, endm1));
        uint4 v = *(const uint4*)(hb + (size_t)i0 * 128 + fl * 8);
        m = pkmax4(m, v);
    }
    m.x = pkmax(m.x, (unsigned)__shfl_xor((int)m.x, 8));
    m.y = pkmax(m.y, (unsigned)__shfl_xor((int)m.y, 8));
    m.z = pkmax(m.z, (unsigned)__shfl_xor((int)m.z, 8));
    m.w = pkmax(m.w, (unsigned)__shfl_xor((int)m.w, 8));

    if (sub == 0) {
        f32x4 a, b;
        a[0] = __uint_as_float(m.x << 16); a[1] = __uint_as_float(m.x & 0xFFFF0000u);
        a[2] = __uint_as_float(m.y << 16); a[3] = __uint_as_float(m.y & 0xFFFF0000u);
        b[0] = __uint_as_float(m.z << 16); b[1] = __uint_as_float(m.z & 0xFFFF0000u);
        b[2] = __uint_as_float(m.w << 16); b[3] = __uint_as_float(m.w & 0xFFFF0000u);
        *(f32x4*)(out + (size_t)n * 128 + 64 + fl * 8) = a;
        *(f32x4*)(out + (size_t)n * 128 + 64 + fl * 8 + 4) = b;
    }
}

// ---------------- launch ----------------

extern "C" void kernel_launch(void* const* d_in, const int* in_sizes, int n_in,
                              void* d_out, int out_size, void* d_ws, size_t ws_size,
                              hipStream_t stream) {
    const float* inputs = (const float*)d_in[0];
    const int*   src    = (const int*)d_in[1];
    const int*   dst    = (const int*)d_in[2];
    const float* Ws     = (const float*)d_in[3];
    const float* bs     = (const float*)d_in[4];
    const float* gs     = (const float*)d_in[5];
    const float* bes    = (const float*)d_in[6];
    float* out = (float*)d_out;

    char* w = (char*)d_ws;
    int* bincur = (int*)w; w += 256 * 4;
    int* rowptr = (int*)w; w += (size_t)(NN + 1) * 4;
    int* deg    = (int*)w; w += (size_t)NN * 4;
    int* eidx   = (int*)w; w += (size_t)NBIN * BCAP * 4;             // 7.25 MB
    uintptr_t a = (uintptr_t)w; a = (a + 255) & ~(uintptr_t)255; w = (char*)a;
    u16* wtb = (u16*)w; w += 3 * (size_t)INF * HID * 2;              // 48 KB
    u16* xbf = (u16*)w; w += (size_t)NN * INF * 2;                   // 25.6 MB
    unsigned* binpair = (unsigned*)w; w += (size_t)NBIN * BCAP * 4;  // 7.25 MB

    const int MLPB = (NN + 63) / 64;   // 1563
    const int GATB = (NN + 15) / 16;   // 6250

    // CSR build (slotted bins)
    k_zero   <<<1,     256, 0, stream>>>(bincur);
    k_binfill<<<FILLB, 256, 0, stream>>>(src, dst, bincur, binpair);
    k_binsort<<<NBIN,  256, 0, stream>>>(binpair, bincur, rowptr, deg, eidx);

    // weights -> bf16 transposed
    k_wconv<<<3, 256, 0, stream>>>(Ws, wtb);

    // layer 0
    k_mlp<0><<<MLPB, 256, 0, stream>>>(inputs, xbf, wtb,          bs,       gs,       bes,       nullptr);
    k_gather_bb<<<GATB, 256, 0, stream>>>(xbf, rowptr, deg, eidx, xbf + 64);
    // layer 1
    k_mlp<1><<<MLPB, 256, 0, stream>>>(nullptr, xbf, wtb + 8192,  bs + 64,  gs + 64,  bes + 64,  nullptr);
    k_gather_bb<<<GATB, 256, 0, stream>>>(xbf, rowptr, deg, eidx, xbf + 64);
    // layer 2
    k_mlp<2><<<MLPB, 256, 0, stream>>>(nullptr, xbf, wtb + 16384, bs + 128, gs + 128, bes + 128, out);
    k_gather_bf<<<GATB, 256, 0, stream>>>(xbf, rowptr, deg, eidx, out);
}

// Round 17
// 186.465 us; speedup vs baseline: 1.0360x; 1.0360x over previous
//
#include <hip/hip_runtime.h>

#define NN 100000
#define NE 1600000
#define INF 128
#define HID 64
#define LN_EPS 1e-5f

#define BINB 9
#define BINSZ 512
#define NBIN 196
#define FILLB 512
#define BCAP 9250   // fixed bin slot capacity (Poisson(8163) + 12 sigma)

typedef unsigned short u16;
typedef __attribute__((ext_vector_type(8))) short bf16x8;
typedef __attribute__((ext_vector_type(4))) float f32x4;

#define SAP 136   // padded LDS row stride (bf16 elems)

__device__ __forceinline__ u16 f2bf(float f) {
    unsigned u = __float_as_uint(f);
    return (u16)((u + 0x7FFFu + ((u >> 16) & 1u)) >> 16);
}
__device__ __forceinline__ unsigned pack2bf(float a, float b) {
    unsigned ua = __float_as_uint(a), ub = __float_as_uint(b);
    ua = (ua + 0x7FFFu + ((ua >> 16) & 1u)) >> 16;
    ub = (ub + 0x7FFFu + ((ub >> 16) & 1u)) >> 16;
    return ua | (ub << 16);
}
__device__ __forceinline__ unsigned pkmax(unsigned a, unsigned b) {
    unsigned r;
    asm("v_pk_max_u16 %0, %1, %2" : "=v"(r) : "v"(a), "v"(b));
    return r;
}
__device__ __forceinline__ uint4 pkmax4(uint4 a, uint4 b) {
    return make_uint4(pkmax(a.x, b.x), pkmax(a.y, b.y), pkmax(a.z, b.z), pkmax(a.w, b.w));
}

// ---------------- CSR build: slotted binned counting sort ----------------

__global__ __launch_bounds__(256) void k_zero(int* __restrict__ bincur) {
    int i = threadIdx.x;
    if (i < NBIN) bincur[i] = 0;
}

__global__ __launch_bounds__(256) void k_binfill(const int* __restrict__ src, const int* __restrict__ dst,
                                                 int* __restrict__ bincur, unsigned* __restrict__ binpair) {
    __shared__ int cnt[NBIN];
    __shared__ int base[NBIN];
    __shared__ int cur[NBIN];
    int tid = threadIdx.x;
    const int chunk = (NE + FILLB - 1) / FILLB;
    int s = blockIdx.x * chunk;
    int t = min(s + chunk, NE);

    for (int i = tid; i < NBIN; i += 256) cnt[i] = 0;
    __syncthreads();
    for (int e = s + tid; e < t; e += 256) atomicAdd(&cnt[dst[e] >> BINB], 1);
    __syncthreads();
    for (int i = tid; i < NBIN; i += 256) {
        int c = cnt[i];
        base[i] = c ? atomicAdd(&bincur[i], c) : 0;
        cur[i] = 0;
    }
    __syncthreads();
    for (int e = s + tid; e < t; e += 256) {
        int d = dst[e];
        int b = d >> BINB;
        int pos = base[b] + atomicAdd(&cur[b], 1);
        binpair[(size_t)b * BCAP + pos] = ((unsigned)src[e] << BINB) | (unsigned)(d & (BINSZ - 1));
    }
}

__global__ __launch_bounds__(256) void k_binsort(const unsigned* __restrict__ binpair,
                                                 const int* __restrict__ bincur,
                                                 int* __restrict__ rowptr, int* __restrict__ deg,
                                                 int* __restrict__ eidx) {
    __shared__ int cnt[BINSZ];
    __shared__ int ofs[BINSZ];
    __shared__ int cur[BINSZ];
    int tid = threadIdx.x, lane = tid & 63, wid = tid >> 6;
    int b = blockIdx.x;
    int s = b * BCAP;
    int t = s + bincur[b];

    cnt[tid] = 0; cnt[tid + 256] = 0;
    __syncthreads();
    for (int e = s + tid; e < t; e += 256) atomicAdd(&cnt[binpair[e] & (BINSZ - 1)], 1);
    __syncthreads();

    int a0 = cnt[2 * tid], a1 = cnt[2 * tid + 1];
    int ps = a0 + a1;
    int v = ps;
    #pragma unroll
    for (int d = 1; d < 64; d <<= 1) { int y = __shfl_up(v, d); if (lane >= d) v += y; }
    __shared__ int wsum[4];
    if (lane == 63) wsum[wid] = v;
    __syncthreads();
    int add = 0;
    for (int w = 0; w < wid; ++w) add += wsum[w];
    int excl = v + add - ps;
    ofs[2 * tid] = excl; ofs[2 * tid + 1] = excl + a0;
    cur[2 * tid] = excl; cur[2 * tid + 1] = excl + a0;
    __syncthreads();

    int nodeBase = b << BINB;
    #pragma unroll
    for (int j = 0; j < 2; ++j) {
        int i = tid + j * 256;
        int n = nodeBase + i;
        if (n < NN) { rowptr[n] = s + ofs[i]; deg[n] = cnt[i]; }
    }

    for (int e = s + tid; e < t; e += 256) {
        unsigned p = binpair[e];
        int l = p & (BINSZ - 1);
        int pos = s + atomicAdd(&cur[l], 1);
        eidx[pos] = (int)(p >> BINB);
    }
}

// ---------------- W convert: f32 [128][64] -> bf16 transposed [64][128] ----------------

__global__ __launch_bounds__(256) void k_wconv(const float* __restrict__ Ws, u16* __restrict__ wtb) {
    int L = blockIdx.x, tid = threadIdx.x;
    int c = tid & 63, k0 = (tid >> 6) * 32;
    const float* W = Ws + (size_t)L * INF * HID;
    alignas(16) u16 tmp[32];
    #pragma unroll
    for (int k = 0; k < 32; ++k) tmp[k] = f2bf(W[(size_t)(k0 + k) * HID + c]);
    u16* dstp = wtb + (size_t)L * HID * INF + (size_t)c * INF + k0;
    #pragma unroll
    for (int j = 0; j < 4; ++j)
        *(uint4*)(dstp + j * 8) = *(uint4*)&tmp[j * 8];
}

// ---------------- MFMA Linear + LayerNorm + ReLU ----------------

template<int KIND>
__global__ __launch_bounds__(256) void k_mlp(
    const float* __restrict__ fin,
    u16* xbf,
    const u16* __restrict__ wtb,
    const float* __restrict__ bias, const float* __restrict__ gam, const float* __restrict__ bet,
    float* __restrict__ fout)
{
    __shared__ u16 sA[64 * SAP];
    __shared__ u16 sB[64 * SAP];

    const int tid = threadIdx.x, lane = tid & 63;
    const int w = __builtin_amdgcn_readfirstlane(tid >> 6);
    const int node0 = blockIdx.x * 64;

    if (KIND == 0) {
        #pragma unroll
        for (int j = 0; j < 8; ++j) {
            int f4 = tid + j * 256;
            int nl = f4 >> 5, k4 = f4 & 31;
            int n = node0 + nl; if (n >= NN) n = NN - 1;
            float4 v = *(const float4*)(fin + (size_t)n * INF + k4 * 4);
            *(uint2*)&sA[nl * SAP + k4 * 4] = make_uint2(pack2bf(v.x, v.y), pack2bf(v.z, v.w));
        }
    } else {
        #pragma unroll
        for (int j = 0; j < 4; ++j) {
            int ch = tid + j * 256;
            int nl = ch >> 4, c8 = ch & 15;
            int n = node0 + nl; if (n >= NN) n = NN - 1;
            *(uint4*)&sA[nl * SAP + c8 * 8] = *(const uint4*)(xbf + (size_t)n * INF + c8 * 8);
        }
    }
    #pragma unroll
    for (int j = 0; j < 4; ++j) {
        int ch = tid + j * 256;
        int r = ch >> 4, k8 = ch & 15;
        *(uint4*)&sB[r * SAP + k8 * 8] = *(const uint4*)(wtb + (size_t)r * INF + k8 * 8);
    }

    const int cl = lane & 15;
    float bC[4], gC[4], tC[4];
    #pragma unroll
    for (int nt = 0; nt < 4; ++nt) {
        int c = nt * 16 + cl;
        bC[nt] = bias[c]; gC[nt] = gam[c]; tC[nt] = bet[c];
    }

    __syncthreads();

    f32x4 acc[4] = {(f32x4)0.f, (f32x4)0.f, (f32x4)0.f, (f32x4)0.f};
    const int kg = (lane >> 4) * 8;
    #pragma unroll
    for (int kk = 0; kk < 4; ++kk) {
        bf16x8 a = *(const bf16x8*)&sA[(w * 16 + cl) * SAP + kk * 32 + kg];
        #pragma unroll
        for (int nt = 0; nt < 4; ++nt) {
            bf16x8 b = *(const bf16x8*)&sB[(nt * 16 + cl) * SAP + kk * 32 + kg];
            acc[nt] = __builtin_amdgcn_mfma_f32_16x16x32_bf16(a, b, acc[nt], 0, 0, 0);
        }
    }

    #pragma unroll
    for (int nt = 0; nt < 4; ++nt)
        #pragma unroll
        for (int r = 0; r < 4; ++r) acc[nt][r] += bC[nt];

    float mu[4], rs[4];
    #pragma unroll
    for (int r = 0; r < 4; ++r) {
        float s = acc[0][r] + acc[1][r] + acc[2][r] + acc[3][r];
        float q = acc[0][r]*acc[0][r] + acc[1][r]*acc[1][r] + acc[2][r]*acc[2][r] + acc[3][r]*acc[3][r];
        #pragma unroll
        for (int m = 1; m < 16; m <<= 1) { s += __shfl_xor(s, m); q += __shfl_xor(q, m); }
        mu[r] = s * 0.015625f;
        float var = fmaxf(q * 0.015625f - mu[r] * mu[r], 0.f);
        rs[r] = rsqrtf(var + LN_EPS);
    }

    #pragma unroll
    for (int nt = 0; nt < 4; ++nt) {
        int c = nt * 16 + cl;
        #pragma unroll
        for (int r = 0; r < 4; ++r) {
            int row = w * 16 + (lane >> 4) * 4 + r;
            float o = fmaxf((acc[nt][r] - mu[r]) * rs[r] * gC[nt] + tC[nt], 0.f);
            sA[row * SAP + c] = f2bf(o);
            if (KIND == 2) {
                int n = node0 + row;
                if (n < NN) fout[(size_t)n * 128 + c] = o;
            }
        }
    }

    #pragma unroll
    for (int i = 0; i < 2; ++i) {
        int ch = lane + i * 64;
        int r16 = ch >> 3, c8 = ch & 7;
        int row = w * 16 + r16;
        int n = node0 + row;
        if (n < NN)
            *(uint4*)(xbf + (size_t)n * INF + c8 * 8) = *(const uint4*)&sA[row * SAP + c8 * 8];
    }
}

// ---------------- per-dst segment max over bf16 rows (paired-edge uint4) ----------------
// group(16 lanes) = 1 dst node, split 2x8: each 8-lane half = a different edge,
// lane = 8 features (uint4). One VMEM instr = 8 rows. v_pk_max_u16 = 2 feats/op.
// Odd-deg tail: clamp e to end-1 (max is idempotent). Final: shfl_xor(8) combine.

__global__ __launch_bounds__(256) void k_gather_bb(
    const u16* __restrict__ hb, const int* __restrict__ rowptr, const int* __restrict__ deg,
    const int* __restrict__ eidx, u16* __restrict__ aggb)
{
    int tid = threadIdx.x, lane = tid & 63, wid = tid >> 6;
    int nw0 = blockIdx.x * 16 + wid * 4;
    int g = lane >> 4, sub = (lane >> 3) & 1, fl = lane & 7;
    int n = nw0 + g;

    int rp = (lane < 4) ? rowptr[nw0 + lane] : 0;
    int dv = (lane < 4) ? deg[nw0 + lane] : 0;
    int start = __shfl(rp, g);
    int dg    = __shfl(dv, g);

    uint4 m = make_uint4(0, 0, 0, 0);
    if (dg == 0) {
        m = *(const uint4*)(hb + (size_t)n * 128 + fl * 8);
    } else {
        int endm1 = start + dg - 1;
        int iters = (dg + 1) >> 1;
        int e = start + sub;
        int it = 0;
        for (; it + 4 <= iters; it += 4, e += 8) {
            int e0 = min(e, endm1),     e1 = min(e + 2, endm1);
            int e2 = min(e + 4, endm1), e3 = min(e + 6, endm1);
            int i0 = eidx[e0], i1 = eidx[e1], i2 = eidx[e2], i3 = eidx[e3];
            uint4 v0 = *(const uint4*)(hb + (size_t)i0 * 128 + fl * 8);
            uint4 v1 = *(const uint4*)(hb + (size_t)i1 * 128 + fl * 8);
            uint4 v2 = *(const uint4*)(hb + (size_t)i2 * 128 + fl * 8);
            uint4 v3 = *(const uint4*)(hb + (size_t)i3 * 128 + fl * 8);
            m = pkmax4(m, pkmax4(pkmax4(v0, v1), pkmax4(v2, v3)));
        }
        for (; it < iters; ++it, e += 2) {
            int e0 = min(e, endm1);
            int i0 = eidx[e0];
            uint4 v = *(const uint4*)(hb + (size_t)i0 * 128 + fl * 8);
            m = pkmax4(m, v);
        }
        m.x = pkmax(m.x, (unsigned)__shfl_xor((int)m.x, 8));
        m.y = pkmax(m.y, (unsigned)__shfl_xor((int)m.y, 8));
        m.z = pkmax(m.z, (unsigned)__shfl_xor((int)m.z, 8));
        m.w = pkmax(m.w, (unsigned)__shfl_xor((int)m.w, 8));
    }
    if (sub == 0)
        *(uint4*)(aggb + (size_t)n * 128 + fl * 8) = m;
}

__global__ __launch_bounds__(256) void k_gather_bf(
    const u16* __restrict__ hb, const int* __restrict__ rowptr, const int* __restrict__ deg,
    const int* __restrict__ eidx, float* __restrict__ out)
{
    int tid = threadIdx.x, lane = tid & 63, wid = tid >> 6;
    int nw0 = blockIdx.x * 16 + wid * 4;
    int g = lane >> 4, sub = (lane >> 3) & 1, fl = lane & 7;
    int n = nw0 + g;

    int rp = (lane < 4) ? rowptr[nw0 + lane] : 0;
    int dv = (lane < 4) ? deg[nw0 + lane] : 0;
    int start = __shfl(rp, g);
    int dg    = __shfl(dv, g);

    if (dg == 0) {   // exact f32 self feature: copy out[n][fl*8..fl*8+8) -> +64
        if (sub == 0) {
            f32x4 a = *(const f32x4*)(out + (size_t)n * 128 + fl * 8);
            f32x4 b = *(const f32x4*)(out + (size_t)n * 128 + fl * 8 + 4);
            *(f32x4*)(out + (size_t)n * 128 + 64 + fl * 8) = a;
            *(f32x4*)(out + (size_t)n * 128 + 64 + fl * 8 + 4) = b;
        }
        return;
    }

    uint4 m = make_uint4(0, 0, 0, 0);
    int endm1 = start + dg - 1;
    int iters = (dg + 1) >> 1;
    int e = start + sub;
    int it = 0;
    for (; it + 4 <= iters; it += 4, e += 8) {
        int e0 = min(e, endm1),     e1 = min(e + 2, endm1);
        int e2 = min(e + 4, endm1), e3 = min(e + 6, endm1);
        int i0 = eidx[e0], i1 = eidx[e1], i2 = eidx[e2], i3 = eidx[e3];
        uint4 v0 = *(const uint4*)(hb + (size_t)i0 * 128 + fl * 8);
        uint4 v1 = *(const uint4*)(hb + (size_t)i1 * 128 + fl * 8);
        uint4 v2 = *(const uint4*)(hb + (size_t)i2 * 128 + fl * 8);
        uint4 v3 = *(const uint4*)(hb + (size_t)i3 * 128 + fl * 8);
        m = pkmax4(m, pkmax4(pkmax4(v0, v1), pkmax4(v2, v3)));
    }
    for (; it < iters; ++it, e += 2) {
        int e0 = min(e, endm1);
        int i0 = eidx[e0];
        uint4 v = *(const uint4*)(hb + (size_t)i0 * 128 + fl * 8);
        m = pkmax4(m, v);
    }
    m.x = pkmax(m.x, (unsigned)__shfl_xor((int)m.x, 8));
    m.y = pkmax(m.y, (unsigned)__shfl_xor((int)m.y, 8));
    m.z = pkmax(m.z, (unsigned)__shfl_xor((int)m.z, 8));
    m.w = pkmax(m.w, (unsigned)__shfl_xor((int)m.w, 8));

    if (sub == 0) {
        f32x4 a, b;
        a[0] = __uint_as_float(m.x << 16); a[1] = __uint_as_float(m.x & 0xFFFF0000u);
        a[2] = __uint_as_float(m.y << 16); a[3] = __uint_as_float(m.y & 0xFFFF0000u);
        b[0] = __uint_as_float(m.z << 16); b[1] = __uint_as_float(m.z & 0xFFFF0000u);
        b[2] = __uint_as_float(m.w << 16); b[3] = __uint_as_float(m.w & 0xFFFF0000u);
        *(f32x4*)(out + (size_t)n * 128 + 64 + fl * 8) = a;
        *(f32x4*)(out + (size_t)n * 128 + 64 + fl * 8 + 4) = b;
    }
}

// ---------------- launch ----------------

extern "C" void kernel_launch(void* const* d_in, const int* in_sizes, int n_in,
                              void* d_out, int out_size, void* d_ws, size_t ws_size,
                              hipStream_t stream) {
    const float* inputs = (const float*)d_in[0];
    const int*   src    = (const int*)d_in[1];
    const int*   dst    = (const int*)d_in[2];
    const float* Ws     = (const float*)d_in[3];
    const float* bs     = (const float*)d_in[4];
    const float* gs     = (const float*)d_in[5];
    const float* bes    = (const float*)d_in[6];
    float* out = (float*)d_out;

    char* w = (char*)d_ws;
    int* bincur = (int*)w; w += 256 * 4;
    int* rowptr = (int*)w; w += (size_t)(NN + 1) * 4;
    int* deg    = (int*)w; w += (size_t)NN * 4;
    int* eidx   = (int*)w; w += (size_t)NBIN * BCAP * 4;             // 7.25 MB
    uintptr_t a = (uintptr_t)w; a = (a + 255) & ~(uintptr_t)255; w = (char*)a;
    u16* wtb = (u16*)w; w += 3 * (size_t)INF * HID * 2;              // 48 KB
    u16* xbf = (u16*)w; w += (size_t)NN * INF * 2;                   // 25.6 MB
    unsigned* binpair = (unsigned*)w; w += (size_t)NBIN * BCAP * 4;  // 7.25 MB

    const int MLPB = (NN + 63) / 64;   // 1563
    const int GATB = (NN + 15) / 16;   // 6250

    // CSR build (slotted bins)
    k_zero   <<<1,     256, 0, stream>>>(bincur);
    k_binfill<<<FILLB, 256, 0, stream>>>(src, dst, bincur, binpair);
    k_binsort<<<NBIN,  256, 0, stream>>>(binpair, bincur, rowptr, deg, eidx);

    // weights -> bf16 transposed
    k_wconv<<<3, 256, 0, stream>>>(Ws, wtb);

    // layer 0
    k_mlp<0><<<MLPB, 256, 0, stream>>>(inputs, xbf, wtb,          bs,       gs,       bes,       nullptr);
    k_gather_bb<<<GATB, 256, 0, stream>>>(xbf, rowptr, deg, eidx, xbf + 64);
    // layer 1
    k_mlp<1><<<MLPB, 256, 0, stream>>>(nullptr, xbf, wtb + 8192,  bs + 64,  gs + 64,  bes + 64,  nullptr);
    k_gather_bb<<<GATB, 256, 0, stream>>>(xbf, rowptr, deg, eidx, xbf + 64);
    // layer 2
    k_mlp<2><<<MLPB, 256, 0, stream>>>(nullptr, xbf, wtb + 16384, bs + 128, gs + 128, bes + 128, out);
    k_gather_bf<<<GATB, 256, 0, stream>>>(xbf, rowptr, deg, eidx, out);
}